// Round 11
// baseline (291.543 us; speedup 1.0000x reference)
//
#include <hip/hip_runtime.h>
#include <cstdint>
#include <cstddef>

#define DEVI __device__ __forceinline__

typedef __attribute__((ext_vector_type(8))) short short8;
typedef __attribute__((ext_vector_type(4))) float f32x4;

constexpr int Bc = 8, Tc = 2048, Cc = 1024;
constexpr int WKV_L = 32, WKV_NCH = 64;   // T = L * NCH

DEVI unsigned short f2b(float f) {
  unsigned int u = __float_as_uint(f);
  unsigned int r = (u + 0x7FFFu + ((u >> 16) & 1u)) >> 16;  // RNE
  return (unsigned short)r;
}
DEVI float b2f(unsigned short u) {
  return __uint_as_float(((unsigned int)u) << 16);
}

DEVI void gload16(const unsigned short* g, unsigned short* l) {
  __builtin_amdgcn_global_load_lds(
      (const __attribute__((address_space(1))) void*)g,
      (__attribute__((address_space(3))) void*)l, 16, 0, 0);
}

#define FENCE() asm volatile("" ::: "memory")

// ------- fused prep: 4 weight converts + time-mix, one dispatch ----------
// blocks 0..4095: weight f32->bf16 (1024 blocks each of Wk,Wv,Wr,Wo)
// blocks 4096..6143: mix3 grid-stride over NE/4
__global__ void prep_kernel(const float* __restrict__ x,
                            const float* __restrict__ Wk,
                            const float* __restrict__ Wv,
                            const float* __restrict__ Wr,
                            const float* __restrict__ Wo,
                            const float* __restrict__ tmk,
                            const float* __restrict__ tmv,
                            const float* __restrict__ tmr,
                            unsigned short* __restrict__ Wk_b,
                            unsigned short* __restrict__ Wv_b,
                            unsigned short* __restrict__ Wr_b,
                            unsigned short* __restrict__ Wo_b,
                            unsigned short* __restrict__ kin,
                            unsigned short* __restrict__ vin,
                            unsigned short* __restrict__ rin) {
  const int bid = blockIdx.x;
  if (bid < 4096) {
    const int s = bid >> 10;
    const float* in = s == 0 ? Wk : (s == 1 ? Wv : (s == 2 ? Wr : Wo));
    unsigned short* out = s == 0 ? Wk_b : (s == 1 ? Wv_b : (s == 2 ? Wr_b : Wo_b));
    const int i = (bid & 1023) * 256 + threadIdx.x;   // [0, CC/4)
    const float4 v = ((const float4*)in)[i];
    ushort4 o;
    o.x = f2b(v.x); o.y = f2b(v.y); o.z = f2b(v.z); o.w = f2b(v.w);
    ((ushort4*)out)[i] = o;
    return;
  }
  const long n4 = (long)Bc * Tc * Cc / 4;
  long i = (long)(bid - 4096) * 256 + threadIdx.x;
  const long stride = 2048L * 256;
  for (; i < n4; i += stride) {
    const long e = i * 4;
    const int c = (int)(e & (Cc - 1));
    const long bt = e >> 10;
    const int t = (int)(bt & (Tc - 1));
    const float4 xv = *(const float4*)(x + e);
    float4 pv = {0.f, 0.f, 0.f, 0.f};
    if (t > 0) pv = *(const float4*)(x + e - Cc);
    const float4 mk = *(const float4*)(tmk + c);
    const float4 mv = *(const float4*)(tmv + c);
    const float4 mr = *(const float4*)(tmr + c);
    const float* xp = (const float*)&xv;
    const float* pp = (const float*)&pv;
    const float* mkp = (const float*)&mk;
    const float* mvp = (const float*)&mv;
    const float* mrp = (const float*)&mr;
    ushort4 ko, vo, ro;
    unsigned short* kop = (unsigned short*)&ko;
    unsigned short* vop = (unsigned short*)&vo;
    unsigned short* rop = (unsigned short*)&ro;
#pragma unroll
    for (int q = 0; q < 4; ++q) {
      kop[q] = f2b(xp[q] * mkp[q] + pp[q] * (1.f - mkp[q]));
      vop[q] = f2b(xp[q] * mvp[q] + pp[q] * (1.f - mvp[q]));
      rop[q] = f2b(xp[q] * mrp[q] + pp[q] * (1.f - mrp[q]));
    }
    *(ushort4*)(kin + e) = ko;
    *(ushort4*)(vin + e) = vo;
    *(ushort4*)(rin + e) = ro;
  }
}

// ---- 128x128 / BK=64 / 4-wave bf16 GEMM, 64KB LDS -> 2 blocks/CU ---------
// C[M][N] = A[M][K] * W[N][K]^T. blockIdx.z selects (A,W,C) triple.
// Sync structure = R5-proven: vmcnt(0)+barrier at top, STAGE(next) after
// barrier, bulk reads + bulk MFMA (compiler schedules). XOR swizzle
// phys 16B slot = s ^ (row&7) via pre-swizzled global source (rule #21),
// row = 128B -> conflict-free (verified 0 conflicts in R5/R8/R9).
// KEY CHANGE vs 256^2: 64KB LDS + <=256 regs/wave -> TWO independent
// blocks per CU (separate barrier domains) -> DS pipe of one block overlaps
// MFMA pipe of the other (m114 wave-level overlap).
template <typename OutT>
__global__ __launch_bounds__(256, 2)
void gemm128(const unsigned short* __restrict__ A0,
             const unsigned short* __restrict__ W0, OutT* __restrict__ C0,
             const unsigned short* __restrict__ A1,
             const unsigned short* __restrict__ W1, OutT* __restrict__ C1,
             const unsigned short* __restrict__ A2,
             const unsigned short* __restrict__ W2, OutT* __restrict__ C2,
             int K, int N) {
  constexpr int BK = 64;
  __shared__ alignas(16) unsigned short As[2][128 * BK];
  __shared__ alignas(16) unsigned short Bs[2][128 * BK];
  const int z = blockIdx.z;
  const unsigned short* A = z == 0 ? A0 : (z == 1 ? A1 : A2);
  const unsigned short* W = z == 0 ? W0 : (z == 1 ? W1 : W2);
  OutT* C_out = z == 0 ? C0 : (z == 1 ? C1 : C2);
  const int m0 = blockIdx.x * 128;
  const int n0 = blockIdx.y * 128;
  const int tid = threadIdx.x;
  const int lane = tid & 63;
  const int w = tid >> 6;            // 0..3
  const int wr = w >> 1, wc = w & 1; // 2x2 wave grid, 64x64 per wave
  const int fr = lane & 15;
  const int ksl = lane >> 4;         // 0..3

  f32x4 acc[4][4];
#pragma unroll
  for (int i = 0; i < 4; ++i)
#pragma unroll
    for (int j = 0; j < 4; ++j) acc[i][j] = (f32x4){0.f, 0.f, 0.f, 0.f};

  // Staging: per operand tile = 128 rows x 8 slots = 1024 x 16B chunks;
  // 256 threads -> 4 chunks/thread/operand.
#define STAGE(buf, kt)                                                        \
  {                                                                           \
    _Pragma("unroll")                                                         \
    for (int cc = 0; cc < 4; ++cc) {                                          \
      const int c = cc * 256 + tid;                                           \
      const int row = c >> 3;                                                 \
      const int gsl = (c & 7) ^ (row & 7);                                    \
      gload16(A + (size_t)(m0 + row) * K + (kt) + gsl * 8,                    \
              &As[buf][(size_t)(cc * 256 + (tid & ~63)) * 8]);                \
      gload16(W + (size_t)(n0 + row) * K + (kt) + gsl * 8,                    \
              &Bs[buf][(size_t)(cc * 256 + (tid & ~63)) * 8]);                \
    }                                                                         \
  }

#define LDSRD(bufp, row, sl) \
  (*(const short8*)&(bufp)[(row) * 64 + ((((sl) ^ ((row) & 7))) * 8)])

  const int nt = K / BK;
  STAGE(0, 0);
  int cur = 0;
  for (int t = 0; t < nt; ++t) {
    asm volatile("s_waitcnt vmcnt(0)" ::: "memory");
    __builtin_amdgcn_s_barrier();   // tile t ready; t-1 reads done
    FENCE();
    if (t + 1 < nt) STAGE(cur ^ 1, (t + 1) * BK);
    const unsigned short* Ab = As[cur];
    const unsigned short* Bb = Bs[cur];
#pragma unroll
    for (int ks = 0; ks < 2; ++ks) {
      const int sl = ks * 4 + ksl;
      short8 af[4], bf[4];
#pragma unroll
      for (int i = 0; i < 4; ++i)
        af[i] = LDSRD(Ab, wr * 64 + i * 16 + fr, sl);
#pragma unroll
      for (int j = 0; j < 4; ++j)
        bf[j] = LDSRD(Bb, wc * 64 + j * 16 + fr, sl);
#pragma unroll
      for (int i = 0; i < 4; ++i)
#pragma unroll
        for (int j = 0; j < 4; ++j)
          acc[i][j] = __builtin_amdgcn_mfma_f32_16x16x32_bf16(af[i], bf[j],
                                                              acc[i][j], 0, 0, 0);
    }
    FENCE();
    cur ^= 1;
  }
#undef STAGE
#undef LDSRD

  // C/D layout: col = lane&15, row = (lane>>4)*4 + q
  const int orow = (lane >> 4) * 4;
  const int ocol = lane & 15;
#pragma unroll
  for (int i = 0; i < 4; ++i)
#pragma unroll
    for (int j = 0; j < 4; ++j) {
      const size_t rbase = (size_t)(m0 + wr * 64 + i * 16 + orow);
      const int cb = n0 + wc * 64 + j * 16 + ocol;
#pragma unroll
      for (int q = 0; q < 4; ++q) {
        const float vq = acc[i][j][q];
        if constexpr (sizeof(OutT) == 2)
          C_out[(rbase + q) * N + cb] = (OutT)f2b(vq);
        else
          C_out[(rbase + q) * N + cb] = (OutT)vq;
      }
    }
}

// ---------------- WKV chunked scan (1 ch/thread, single-exp updates) -------
__global__ void wkv_phase1(const unsigned short* __restrict__ keyb,
                           const unsigned short* __restrict__ valb,
                           const float* __restrict__ td,
                           float* __restrict__ s_num,
                           float* __restrict__ s_den,
                           float* __restrict__ s_mx) {
  const int g = blockIdx.x * blockDim.x + threadIdx.x;  // [0, B*NCH*C)
  const int c = g & (Cc - 1);
  const int j = (g / Cc) & (WKV_NCH - 1);
  const int b = g / (Cc * WKV_NCH);
  const float w = -__expf(td[c]);
  float num = 0.f, den = 0.f, mx = -1e38f;
  size_t idx = ((size_t)b * Tc + (size_t)j * WKV_L) * Cc + c;
#pragma unroll 4
  for (int i = 0; i < WKV_L; ++i, idx += Cc) {
    const float kt = b2f(keyb[idx]);
    const float vt = b2f(valb[idx]);
    const float mw = mx + w;
    const bool cg = mw >= kt;
    const float d = __expf(cg ? kt - mw : mw - kt);
    const float a1 = cg ? 1.f : d;
    const float a2 = cg ? d : 1.f;
    num = a1 * num + a2 * vt;
    den = a1 * den + a2;
    mx = cg ? mw : kt;
  }
  s_num[g] = num; s_den[g] = den; s_mx[g] = mx;
}

__global__ void wkv_phase2(const float* __restrict__ td,
                           float* __restrict__ s_num,
                           float* __restrict__ s_den,
                           float* __restrict__ s_mx) {
  const int g = blockIdx.x * blockDim.x + threadIdx.x;  // [0, B*C)
  const int c = g & (Cc - 1);
  const int b = g / Cc;
  const float Lw = -__expf(td[c]) * (float)WKV_L;
  float num = 0.f, den = 0.f, mx = -1e38f;
  size_t base = (size_t)b * WKV_NCH * Cc + c;
  for (int j = 0; j < WKV_NCH; ++j) {
    const size_t s = base + (size_t)j * Cc;
    const float ln = s_num[s], ld = s_den[s], lm = s_mx[s];
    s_num[s] = num; s_den[s] = den; s_mx[s] = mx;  // exclusive prefix
    const float md = mx + Lw;
    const bool cg = md >= lm;
    const float d = __expf(cg ? lm - md : md - lm);
    const float e1 = cg ? 1.f : d;
    const float e2 = cg ? d : 1.f;
    num = e1 * num + e2 * ln;
    den = e1 * den + e2 * ld;
    mx = cg ? md : lm;
  }
}

__global__ void wkv_phase3(const unsigned short* __restrict__ keyb,
                           const unsigned short* __restrict__ valb,
                           const unsigned short* __restrict__ recb,
                           const float* __restrict__ td,
                           const float* __restrict__ tf,
                           const float* __restrict__ s_num,
                           const float* __restrict__ s_den,
                           const float* __restrict__ s_mx,
                           unsigned short* __restrict__ rwkv) {
  const int g = blockIdx.x * blockDim.x + threadIdx.x;  // [0, B*NCH*C)
  const int c = g & (Cc - 1);
  const int j = (g / Cc) & (WKV_NCH - 1);
  const int b = g / (Cc * WKV_NCH);
  const float w = -__expf(td[c]);
  const float u = tf[c];
  float num = s_num[g], den = s_den[g], mx = s_mx[g];
  size_t idx = ((size_t)b * Tc + (size_t)j * WKV_L) * Cc + c;
#pragma unroll 2
  for (int i = 0; i < WKV_L; ++i, idx += Cc) {
    const float kt = b2f(keyb[idx]);
    const float vt = b2f(valb[idx]);
    const float rt = b2f(recb[idx]);
    const float ku = kt + u;
    const bool co = mx >= ku;
    const float dd = __expf(co ? ku - mx : mx - ku);
    const float e1 = co ? 1.f : dd;
    const float e2 = co ? dd : 1.f;
    const float out = (e1 * num + e2 * vt) / (e1 * den + e2);
    const float sr = 1.f / (1.f + __expf(-rt));
    rwkv[idx] = f2b(sr * out);
    const float mw = mx + w;
    const bool cg = mw >= kt;
    const float du = __expf(cg ? kt - mw : mw - kt);
    const float a1 = cg ? 1.f : du;
    const float a2 = cg ? du : 1.f;
    num = a1 * num + a2 * vt;
    den = a1 * den + a2;
    mx = cg ? mw : kt;
  }
}

extern "C" void kernel_launch(void* const* d_in, const int* in_sizes, int n_in,
                              void* d_out, int out_size, void* d_ws, size_t ws_size,
                              hipStream_t stream) {
  const float* x   = (const float*)d_in[0];
  const float* Wk  = (const float*)d_in[1];
  const float* Wv  = (const float*)d_in[2];
  const float* Wr  = (const float*)d_in[3];
  const float* Wo  = (const float*)d_in[4];
  const float* td  = (const float*)d_in[5];
  const float* tf  = (const float*)d_in[6];
  const float* tmk = (const float*)d_in[7];
  const float* tmv = (const float*)d_in[8];
  const float* tmr = (const float*)d_in[9];

  const long BT = (long)Bc * Tc;     // 16384
  const long NE = BT * Cc;           // 16,777,216
  const long CC = (long)Cc * Cc;     // 1,048,576

  // Workspace carve (~200 MB)
  char* p = (char*)d_ws;
  unsigned short* Wk_b = (unsigned short*)p; p += CC * 2;
  unsigned short* Wv_b = (unsigned short*)p; p += CC * 2;
  unsigned short* Wr_b = (unsigned short*)p; p += CC * 2;
  unsigned short* Wo_b = (unsigned short*)p; p += CC * 2;
  unsigned short* kin  = (unsigned short*)p; p += NE * 2;
  unsigned short* vin  = (unsigned short*)p; p += NE * 2;
  unsigned short* rin  = (unsigned short*)p; p += NE * 2;
  unsigned short* keyb = (unsigned short*)p; p += NE * 2;
  unsigned short* valb = (unsigned short*)p; p += NE * 2;
  unsigned short* recb = (unsigned short*)p; p += NE * 2;
  // aliases: rwkv reuses kin (dead after key GEMM); s_* reuse vin (dead after
  // value GEMM). 3 x 2MB well within vin's 32MB.
  unsigned short* rwkv = kin;
  const long NS = (long)Bc * WKV_NCH * Cc;  // 524288
  float* s_num = (float*)vin;
  float* s_den = s_num + NS;
  float* s_mx  = s_den + NS;

  // 1+2. weight converts + time-mix (one dispatch)
  prep_kernel<<<6144, 256, 0, stream>>>(x, Wk, Wv, Wr, Wo, tmk, tmv, tmr,
                                        Wk_b, Wv_b, Wr_b, Wo_b, kin, vin, rin);

  // 3. K/V/R GEMMs (K=1024), batched via blockIdx.z, bf16 outputs
  {
    dim3 grid((unsigned)(BT / 128), (unsigned)(Cc / 128), 3), blk(256);
    gemm128<unsigned short><<<grid, blk, 0, stream>>>(
        kin, Wk_b, keyb, vin, Wv_b, valb, rin, Wr_b, recb, Cc, Cc);
  }

  // 4. WKV chunked scan + sigmoid gate -> rwkv bf16
  wkv_phase1<<<2048, 256, 0, stream>>>(keyb, valb, td, s_num, s_den, s_mx);
  wkv_phase2<<<32, 256, 0, stream>>>(td, s_num, s_den, s_mx);
  wkv_phase3<<<2048, 256, 0, stream>>>(keyb, valb, recb, td, tf,
                                       s_num, s_den, s_mx, rwkv);

  // 5. output GEMM -> d_out (f32)
  {
    dim3 grid((unsigned)(BT / 128), (unsigned)(Cc / 128), 1), blk(256);
    gemm128<float><<<grid, blk, 0, stream>>>(
        rwkv, Wo_b, (float*)d_out, rwkv, Wo_b, (float*)d_out,
        rwkv, Wo_b, (float*)d_out, Cc, Cc);
  }
}

// Round 12
// 263.498 us; speedup vs baseline: 1.1064x; 1.1064x over previous
//
#include <hip/hip_runtime.h>
#include <cstdint>
#include <cstddef>

#define DEVI __device__ __forceinline__

typedef __attribute__((ext_vector_type(8))) short short8;
typedef __attribute__((ext_vector_type(4))) float f32x4;

constexpr int Bc = 8, Tc = 2048, Cc = 1024;
constexpr int WKV_L = 32, WKV_NCH = 64;   // T = L * NCH

DEVI unsigned short f2b(float f) {
  unsigned int u = __float_as_uint(f);
  unsigned int r = (u + 0x7FFFu + ((u >> 16) & 1u)) >> 16;  // RNE
  return (unsigned short)r;
}
DEVI float b2f(unsigned short u) {
  return __uint_as_float(((unsigned int)u) << 16);
}

DEVI void gload16(const unsigned short* g, unsigned short* l) {
  __builtin_amdgcn_global_load_lds(
      (const __attribute__((address_space(1))) void*)g,
      (__attribute__((address_space(3))) void*)l, 16, 0, 0);
}

#define FENCE() asm volatile("" ::: "memory")

// ---------------- f32 -> bf16 convert (all 4 weights, one dispatch) --------
__global__ void convert4_kernel(const float* __restrict__ W0,
                                const float* __restrict__ W1,
                                const float* __restrict__ W2,
                                const float* __restrict__ W3,
                                unsigned short* __restrict__ o0,
                                unsigned short* __restrict__ o1,
                                unsigned short* __restrict__ o2,
                                unsigned short* __restrict__ o3) {
  const int i = blockIdx.x * blockDim.x + threadIdx.x;   // [0, CC/4)
  const int s = blockIdx.y;
  const float* in = s == 0 ? W0 : (s == 1 ? W1 : (s == 2 ? W2 : W3));
  unsigned short* out = s == 0 ? o0 : (s == 1 ? o1 : (s == 2 ? o2 : o3));
  const float4 v = ((const float4*)in)[i];
  ushort4 o;
  o.x = f2b(v.x); o.y = f2b(v.y); o.z = f2b(v.z); o.w = f2b(v.w);
  ((ushort4*)out)[i] = o;
}

// ---------------- time-mix (k,v,r) + bf16 cast ----------------
__global__ void mix3_kernel(const float* __restrict__ x,
                            const float* __restrict__ tmk,
                            const float* __restrict__ tmv,
                            const float* __restrict__ tmr,
                            unsigned short* __restrict__ kin,
                            unsigned short* __restrict__ vin,
                            unsigned short* __restrict__ rin,
                            long n4) {
  long i = (long)blockIdx.x * blockDim.x + threadIdx.x;
  const long stride = (long)gridDim.x * blockDim.x;
  for (; i < n4; i += stride) {
    const long e = i * 4;
    const int c = (int)(e & (Cc - 1));
    const long bt = e >> 10;
    const int t = (int)(bt & (Tc - 1));
    const float4 xv = *(const float4*)(x + e);
    float4 pv = {0.f, 0.f, 0.f, 0.f};
    if (t > 0) pv = *(const float4*)(x + e - Cc);
    const float4 mk = *(const float4*)(tmk + c);
    const float4 mv = *(const float4*)(tmv + c);
    const float4 mr = *(const float4*)(tmr + c);
    const float* xp = (const float*)&xv;
    const float* pp = (const float*)&pv;
    const float* mkp = (const float*)&mk;
    const float* mvp = (const float*)&mv;
    const float* mrp = (const float*)&mr;
    ushort4 ko, vo, ro;
    unsigned short* kop = (unsigned short*)&ko;
    unsigned short* vop = (unsigned short*)&vo;
    unsigned short* rop = (unsigned short*)&ro;
#pragma unroll
    for (int q = 0; q < 4; ++q) {
      kop[q] = f2b(xp[q] * mkp[q] + pp[q] * (1.f - mkp[q]));
      vop[q] = f2b(xp[q] * mvp[q] + pp[q] * (1.f - mvp[q]));
      rop[q] = f2b(xp[q] * mrp[q] + pp[q] * (1.f - mrp[q]));
    }
    *(ushort4*)(kin + e) = ko;
    *(ushort4*)(vin + e) = vo;
    *(ushort4*)(rin + e) = ro;
  }
}

// -------- 256x256 / BK=64 / 8-wave bf16 GEMM, chunk-pipelined + T1 swizzle --
// C[M][N] = A[M][K] * W[N][K]^T. blockIdx.z selects (A,W,C) triple.
// Identical to R9's kernel (best measured) EXCEPT XCD-aware tile remap:
// h = x + 64y; m_idx = (h&7)*8 + (h>>3)&7; n_idx = h>>6 (bijective, 256%8=0).
// XCD g (= h%8 under round-robin dispatch) owns m in [8g,8g+8) x all n ->
// A-panel 4x re-reads and the 2MB W panel become L2 hits instead of L3
// traffic (staging delivery was the measured ~6000 cyc/tile bound).
template <typename OutT>
__global__ __launch_bounds__(512, 2)
void gemm256(const unsigned short* __restrict__ A0,
             const unsigned short* __restrict__ W0, OutT* __restrict__ C0,
             const unsigned short* __restrict__ A1,
             const unsigned short* __restrict__ W1, OutT* __restrict__ C1,
             const unsigned short* __restrict__ A2,
             const unsigned short* __restrict__ W2, OutT* __restrict__ C2,
             int K, int N) {
  constexpr int BK = 64;
  __shared__ alignas(16) unsigned short As[2][256 * BK];
  __shared__ alignas(16) unsigned short Bs[2][256 * BK];
  const int z = blockIdx.z;
  const unsigned short* A = z == 0 ? A0 : (z == 1 ? A1 : A2);
  const unsigned short* W = z == 0 ? W0 : (z == 1 ? W1 : W2);
  OutT* C_out = z == 0 ? C0 : (z == 1 ? C1 : C2);
  const int h = (int)blockIdx.x + ((int)blockIdx.y << 6);  // [0,256)
  const int m0 = ((((h & 7) << 3) | ((h >> 3) & 7))) << 8;
  const int n0 = (h >> 6) << 8;
  const int tid = threadIdx.x;
  const int lane = tid & 63;
  const int w = tid >> 6;            // 0..7
  const int wm = w >> 2;             // 0..1  (row half)
  const int wn = w & 3;              // 0..3  (col quarter)
  const int fr = lane & 15;
  const int ksl = lane >> 4;         // 0..3: 8-elem k-subslot within 32

  f32x4 acc[8][4];
#pragma unroll
  for (int i = 0; i < 8; ++i)
#pragma unroll
    for (int j = 0; j < 4; ++j) acc[i][j] = (f32x4){0.f, 0.f, 0.f, 0.f};

#define STAGE(buf, kt)                                                        \
  {                                                                           \
    _Pragma("unroll")                                                         \
    for (int cc = 0; cc < 4; ++cc) {                                          \
      const int c = w * 256 + cc * 64 + lane;                                 \
      const int row = c >> 3;                                                 \
      const int gsl = (c & 7) ^ (row & 7);                                    \
      gload16(A + (size_t)(m0 + row) * K + (kt) + gsl * 8,                    \
              &As[buf][(w * 256 + cc * 64) * 8]);                             \
      gload16(W + (size_t)(n0 + row) * K + (kt) + gsl * 8,                    \
              &Bs[buf][(w * 256 + cc * 64) * 8]);                             \
    }                                                                         \
  }

#define LDSRD(bufp, row, sl) \
  (*(const short8*)&(bufp)[(row) * 64 + ((((sl) ^ ((row) & 7))) * 8)])

  const int nt = K / BK;
  STAGE(0, 0);
  int cur = 0;
  for (int t = 0; t < nt; ++t) {
    asm volatile("s_waitcnt vmcnt(0)" ::: "memory");
    __builtin_amdgcn_s_barrier();   // collective: tile t ready; t-1 reads done
    FENCE();
    if (t + 1 < nt) STAGE(cur ^ 1, (t + 1) * BK);
    const unsigned short* Ab = As[cur];
    const unsigned short* Bb = Bs[cur];
    const int sl0 = ksl;            // logical 16B slot, k-slice 0
    const int sl1 = 4 + ksl;        // k-slice 1
    short8 a0[4], b0[4], a1g[4], a2g[4], b2[4], a3[4];
    // chunk0 reads: A rows 0-63 @ks0, B @ks0
#pragma unroll
    for (int i = 0; i < 4; ++i)
      a0[i] = LDSRD(Ab, wm * 128 + i * 16 + fr, sl0);
#pragma unroll
    for (int j = 0; j < 4; ++j)
      b0[j] = LDSRD(Bb, wn * 64 + j * 16 + fr, sl0);
    // chunk1 reads: A rows 64-127 @ks0
#pragma unroll
    for (int i = 0; i < 4; ++i)
      a1g[i] = LDSRD(Ab, wm * 128 + (4 + i) * 16 + fr, sl0);
    // MFMA chunk0
#pragma unroll
    for (int i = 0; i < 4; ++i)
#pragma unroll
      for (int j = 0; j < 4; ++j)
        acc[i][j] = __builtin_amdgcn_mfma_f32_16x16x32_bf16(a0[i], b0[j],
                                                            acc[i][j], 0, 0, 0);
    // chunk2 reads: A rows 0-63 @ks1, B @ks1
#pragma unroll
    for (int i = 0; i < 4; ++i)
      a2g[i] = LDSRD(Ab, wm * 128 + i * 16 + fr, sl1);
#pragma unroll
    for (int j = 0; j < 4; ++j)
      b2[j] = LDSRD(Bb, wn * 64 + j * 16 + fr, sl1);
    // MFMA chunk1
#pragma unroll
    for (int i = 0; i < 4; ++i)
#pragma unroll
      for (int j = 0; j < 4; ++j)
        acc[4 + i][j] = __builtin_amdgcn_mfma_f32_16x16x32_bf16(a1g[i], b0[j],
                                                                acc[4 + i][j], 0, 0, 0);
    // chunk3 reads: A rows 64-127 @ks1
#pragma unroll
    for (int i = 0; i < 4; ++i)
      a3[i] = LDSRD(Ab, wm * 128 + (4 + i) * 16 + fr, sl1);
    // MFMA chunk2
#pragma unroll
    for (int i = 0; i < 4; ++i)
#pragma unroll
      for (int j = 0; j < 4; ++j)
        acc[i][j] = __builtin_amdgcn_mfma_f32_16x16x32_bf16(a2g[i], b2[j],
                                                            acc[i][j], 0, 0, 0);
    // MFMA chunk3
#pragma unroll
    for (int i = 0; i < 4; ++i)
#pragma unroll
      for (int j = 0; j < 4; ++j)
        acc[4 + i][j] = __builtin_amdgcn_mfma_f32_16x16x32_bf16(a3[i], b2[j],
                                                                acc[4 + i][j], 0, 0, 0);
    FENCE();
    cur ^= 1;
  }
#undef STAGE
#undef LDSRD

  // C/D layout: col = lane&15, row = (lane>>4)*4 + q
  const int orow = (lane >> 4) * 4;
  const int ocol = lane & 15;
#pragma unroll
  for (int i = 0; i < 8; ++i)
#pragma unroll
    for (int j = 0; j < 4; ++j) {
      const size_t rbase = (size_t)(m0 + wm * 128 + i * 16 + orow);
      const int cb = n0 + wn * 64 + j * 16 + ocol;
#pragma unroll
      for (int q = 0; q < 4; ++q) {
        const float vq = acc[i][j][q];
        if constexpr (sizeof(OutT) == 2)
          C_out[(rbase + q) * N + cb] = (OutT)f2b(vq);
        else
          C_out[(rbase + q) * N + cb] = (OutT)vq;
      }
    }
}

// ---------------- WKV chunked scan (1 ch/thread, single-exp updates) -------
__global__ void wkv_phase1(const unsigned short* __restrict__ keyb,
                           const unsigned short* __restrict__ valb,
                           const float* __restrict__ td,
                           float* __restrict__ s_num,
                           float* __restrict__ s_den,
                           float* __restrict__ s_mx) {
  const int g = blockIdx.x * blockDim.x + threadIdx.x;  // [0, B*NCH*C)
  const int c = g & (Cc - 1);
  const int j = (g / Cc) & (WKV_NCH - 1);
  const int b = g / (Cc * WKV_NCH);
  const float w = -__expf(td[c]);
  float num = 0.f, den = 0.f, mx = -1e38f;
  size_t idx = ((size_t)b * Tc + (size_t)j * WKV_L) * Cc + c;
#pragma unroll 4
  for (int i = 0; i < WKV_L; ++i, idx += Cc) {
    const float kt = b2f(keyb[idx]);
    const float vt = b2f(valb[idx]);
    const float mw = mx + w;
    const bool cg = mw >= kt;
    const float d = __expf(cg ? kt - mw : mw - kt);
    const float a1 = cg ? 1.f : d;
    const float a2 = cg ? d : 1.f;
    num = a1 * num + a2 * vt;
    den = a1 * den + a2;
    mx = cg ? mw : kt;
  }
  s_num[g] = num; s_den[g] = den; s_mx[g] = mx;
}

__global__ void wkv_phase2(const float* __restrict__ td,
                           float* __restrict__ s_num,
                           float* __restrict__ s_den,
                           float* __restrict__ s_mx) {
  const int g = blockIdx.x * blockDim.x + threadIdx.x;  // [0, B*C)
  const int c = g & (Cc - 1);
  const int b = g / Cc;
  const float Lw = -__expf(td[c]) * (float)WKV_L;
  float num = 0.f, den = 0.f, mx = -1e38f;
  size_t base = (size_t)b * WKV_NCH * Cc + c;
  for (int j = 0; j < WKV_NCH; ++j) {
    const size_t s = base + (size_t)j * Cc;
    const float ln = s_num[s], ld = s_den[s], lm = s_mx[s];
    s_num[s] = num; s_den[s] = den; s_mx[s] = mx;  // exclusive prefix
    const float md = mx + Lw;
    const bool cg = md >= lm;
    const float d = __expf(cg ? lm - md : md - lm);
    const float e1 = cg ? 1.f : d;
    const float e2 = cg ? d : 1.f;
    num = e1 * num + e2 * ln;
    den = e1 * den + e2 * ld;
    mx = cg ? md : lm;
  }
}

__global__ void wkv_phase3(const unsigned short* __restrict__ keyb,
                           const unsigned short* __restrict__ valb,
                           const unsigned short* __restrict__ recb,
                           const float* __restrict__ td,
                           const float* __restrict__ tf,
                           const float* __restrict__ s_num,
                           const float* __restrict__ s_den,
                           const float* __restrict__ s_mx,
                           unsigned short* __restrict__ rwkv) {
  const int g = blockIdx.x * blockDim.x + threadIdx.x;  // [0, B*NCH*C)
  const int c = g & (Cc - 1);
  const int j = (g / Cc) & (WKV_NCH - 1);
  const int b = g / (Cc * WKV_NCH);
  const float w = -__expf(td[c]);
  const float u = tf[c];
  float num = s_num[g], den = s_den[g], mx = s_mx[g];
  size_t idx = ((size_t)b * Tc + (size_t)j * WKV_L) * Cc + c;
#pragma unroll 2
  for (int i = 0; i < WKV_L; ++i, idx += Cc) {
    const float kt = b2f(keyb[idx]);
    const float vt = b2f(valb[idx]);
    const float rt = b2f(recb[idx]);
    const float ku = kt + u;
    const bool co = mx >= ku;
    const float dd = __expf(co ? ku - mx : mx - ku);
    const float e1 = co ? 1.f : dd;
    const float e2 = co ? dd : 1.f;
    const float out = (e1 * num + e2 * vt) / (e1 * den + e2);
    const float sr = 1.f / (1.f + __expf(-rt));
    rwkv[idx] = f2b(sr * out);
    const float mw = mx + w;
    const bool cg = mw >= kt;
    const float du = __expf(cg ? kt - mw : mw - kt);
    const float a1 = cg ? 1.f : du;
    const float a2 = cg ? du : 1.f;
    num = a1 * num + a2 * vt;
    den = a1 * den + a2;
    mx = cg ? mw : kt;
  }
}

extern "C" void kernel_launch(void* const* d_in, const int* in_sizes, int n_in,
                              void* d_out, int out_size, void* d_ws, size_t ws_size,
                              hipStream_t stream) {
  const float* x   = (const float*)d_in[0];
  const float* Wk  = (const float*)d_in[1];
  const float* Wv  = (const float*)d_in[2];
  const float* Wr  = (const float*)d_in[3];
  const float* Wo  = (const float*)d_in[4];
  const float* td  = (const float*)d_in[5];
  const float* tf  = (const float*)d_in[6];
  const float* tmk = (const float*)d_in[7];
  const float* tmv = (const float*)d_in[8];
  const float* tmr = (const float*)d_in[9];

  const long BT = (long)Bc * Tc;     // 16384
  const long NE = BT * Cc;           // 16,777,216
  const long CC = (long)Cc * Cc;     // 1,048,576

  // Workspace carve (~200 MB)
  char* p = (char*)d_ws;
  unsigned short* Wk_b = (unsigned short*)p; p += CC * 2;
  unsigned short* Wv_b = (unsigned short*)p; p += CC * 2;
  unsigned short* Wr_b = (unsigned short*)p; p += CC * 2;
  unsigned short* Wo_b = (unsigned short*)p; p += CC * 2;
  unsigned short* kin  = (unsigned short*)p; p += NE * 2;
  unsigned short* vin  = (unsigned short*)p; p += NE * 2;
  unsigned short* rin  = (unsigned short*)p; p += NE * 2;
  unsigned short* keyb = (unsigned short*)p; p += NE * 2;
  unsigned short* valb = (unsigned short*)p; p += NE * 2;
  unsigned short* recb = (unsigned short*)p; p += NE * 2;
  // aliases: rwkv reuses kin (dead after key GEMM); s_* reuse vin (dead after
  // value GEMM). 3 x 2MB well within vin's 32MB.
  unsigned short* rwkv = kin;
  const long NS = (long)Bc * WKV_NCH * Cc;  // 524288
  float* s_num = (float*)vin;
  float* s_den = s_num + NS;
  float* s_mx  = s_den + NS;

  // 1. weights -> bf16 (single dispatch)
  {
    dim3 g((unsigned)(CC / 4 / 256), 4), b_(256);
    convert4_kernel<<<g, b_, 0, stream>>>(Wk, Wv, Wr, Wo,
                                          Wk_b, Wv_b, Wr_b, Wo_b);
  }

  // 2. time-mix + cast
  mix3_kernel<<<2048, 256, 0, stream>>>(x, tmk, tmv, tmr, kin, vin, rin, NE / 4);

  // 3. K/V/R GEMMs (K=1024), batched via blockIdx.z, bf16 outputs
  {
    dim3 grid((unsigned)(BT / 256), (unsigned)(Cc / 256), 3), blk(512);
    gemm256<unsigned short><<<grid, blk, 0, stream>>>(
        kin, Wk_b, keyb, vin, Wv_b, valb, rin, Wr_b, recb, Cc, Cc);
  }

  // 4. WKV chunked scan + sigmoid gate -> rwkv bf16
  wkv_phase1<<<2048, 256, 0, stream>>>(keyb, valb, td, s_num, s_den, s_mx);
  wkv_phase2<<<32, 256, 0, stream>>>(td, s_num, s_den, s_mx);
  wkv_phase3<<<2048, 256, 0, stream>>>(keyb, valb, recb, td, tf,
                                       s_num, s_den, s_mx, rwkv);

  // 5. output GEMM -> d_out (f32)
  {
    dim3 grid((unsigned)(BT / 256), (unsigned)(Cc / 256), 1), blk(512);
    gemm256<float><<<grid, blk, 0, stream>>>(
        rwkv, Wo_b, (float*)d_out, rwkv, Wo_b, (float*)d_out,
        rwkv, Wo_b, (float*)d_out, Cc, Cc);
  }
}

// Round 13
// 258.529 us; speedup vs baseline: 1.1277x; 1.0192x over previous
//
#include <hip/hip_runtime.h>
#include <cstdint>
#include <cstddef>

#define DEVI __device__ __forceinline__

typedef __attribute__((ext_vector_type(8))) short short8;
typedef __attribute__((ext_vector_type(4))) float f32x4;

constexpr int Bc = 8, Tc = 2048, Cc = 1024;
constexpr int WKV_L = 32, WKV_NCH = 64;   // T = L * NCH

DEVI unsigned short f2b(float f) {
  unsigned int u = __float_as_uint(f);
  unsigned int r = (u + 0x7FFFu + ((u >> 16) & 1u)) >> 16;  // RNE
  return (unsigned short)r;
}
DEVI float b2f(unsigned short u) {
  return __uint_as_float(((unsigned int)u) << 16);
}

DEVI void gload16(const unsigned short* g, unsigned short* l) {
  __builtin_amdgcn_global_load_lds(
      (const __attribute__((address_space(1))) void*)g,
      (__attribute__((address_space(3))) void*)l, 16, 0, 0);
}

#define FENCE() asm volatile("" ::: "memory")

// ---------------- f32 -> bf16 convert (all 4 weights, one dispatch) --------
__global__ void convert4_kernel(const float* __restrict__ W0,
                                const float* __restrict__ W1,
                                const float* __restrict__ W2,
                                const float* __restrict__ W3,
                                unsigned short* __restrict__ o0,
                                unsigned short* __restrict__ o1,
                                unsigned short* __restrict__ o2,
                                unsigned short* __restrict__ o3) {
  const int i = blockIdx.x * blockDim.x + threadIdx.x;   // [0, CC/4)
  const int s = blockIdx.y;
  const float* in = s == 0 ? W0 : (s == 1 ? W1 : (s == 2 ? W2 : W3));
  unsigned short* out = s == 0 ? o0 : (s == 1 ? o1 : (s == 2 ? o2 : o3));
  const float4 v = ((const float4*)in)[i];
  ushort4 o;
  o.x = f2b(v.x); o.y = f2b(v.y); o.z = f2b(v.z); o.w = f2b(v.w);
  ((ushort4*)out)[i] = o;
}

// ---------------- time-mix (k,v,r) + bf16 cast ----------------
__global__ void mix3_kernel(const float* __restrict__ x,
                            const float* __restrict__ tmk,
                            const float* __restrict__ tmv,
                            const float* __restrict__ tmr,
                            unsigned short* __restrict__ kin,
                            unsigned short* __restrict__ vin,
                            unsigned short* __restrict__ rin,
                            long n4) {
  long i = (long)blockIdx.x * blockDim.x + threadIdx.x;
  const long stride = (long)gridDim.x * blockDim.x;
  for (; i < n4; i += stride) {
    const long e = i * 4;
    const int c = (int)(e & (Cc - 1));
    const long bt = e >> 10;
    const int t = (int)(bt & (Tc - 1));
    const float4 xv = *(const float4*)(x + e);
    float4 pv = {0.f, 0.f, 0.f, 0.f};
    if (t > 0) pv = *(const float4*)(x + e - Cc);
    const float4 mk = *(const float4*)(tmk + c);
    const float4 mv = *(const float4*)(tmv + c);
    const float4 mr = *(const float4*)(tmr + c);
    const float* xp = (const float*)&xv;
    const float* pp = (const float*)&pv;
    const float* mkp = (const float*)&mk;
    const float* mvp = (const float*)&mv;
    const float* mrp = (const float*)&mr;
    ushort4 ko, vo, ro;
    unsigned short* kop = (unsigned short*)&ko;
    unsigned short* vop = (unsigned short*)&vo;
    unsigned short* rop = (unsigned short*)&ro;
#pragma unroll
    for (int q = 0; q < 4; ++q) {
      kop[q] = f2b(xp[q] * mkp[q] + pp[q] * (1.f - mkp[q]));
      vop[q] = f2b(xp[q] * mvp[q] + pp[q] * (1.f - mvp[q]));
      rop[q] = f2b(xp[q] * mrp[q] + pp[q] * (1.f - mrp[q]));
    }
    *(ushort4*)(kin + e) = ko;
    *(ushort4*)(vin + e) = vo;
    *(ushort4*)(rin + e) = ro;
  }
}

// ---- 256x256 / BK=64 / 8-wave bf16 GEMM, 4-phase counted-vmcnt schedule ----
// C[M][N] = A[M][K] * W[N][K]^T. blockIdx.z selects (A,W,C) triple.
// m201-derived schedule adapted to this wave mapping:
//  * owner-group spread staging (2 gloads/wave/phase) of tile t+1:
//      p0: B-half(wn>>1) rows 0-63   p1: B-half rows 64-127
//      p2: A-half(wm)   rows 0-63   p3: A-half rows 64-127
//    -> every phase's ds_reads touch data staged >=2 phases earlier.
//  * uniform vmcnt(4) before each phase's first barrier: 4 loads stay in
//    flight across barriers, NEVER drained in the main loop (T4 = the gain).
//  * two barriers/phase: barrier1 (after vmcnt) opens reads; barrier2 (after
//    MFMA, whose lgkmcnt implies reads done) makes next-phase staging
//    race-free. T5 setprio around MFMA (role-split now exists).
// XOR swizzle phys 16B slot = s ^ (row&7) via pre-swizzled global source
// (0 conflicts, verified R5-R11). XCD remap (T1) kept from R11.
template <typename OutT>
__global__ __launch_bounds__(512, 2)
void gemm256e(const unsigned short* __restrict__ A0,
              const unsigned short* __restrict__ W0, OutT* __restrict__ C0,
              const unsigned short* __restrict__ A1,
              const unsigned short* __restrict__ W1, OutT* __restrict__ C1,
              const unsigned short* __restrict__ A2,
              const unsigned short* __restrict__ W2, OutT* __restrict__ C2,
              int K, int N) {
  constexpr int BK = 64;
  __shared__ alignas(16) unsigned short As[2][256 * BK];
  __shared__ alignas(16) unsigned short Bs[2][256 * BK];
  const int z = blockIdx.z;
  const unsigned short* A = z == 0 ? A0 : (z == 1 ? A1 : A2);
  const unsigned short* W = z == 0 ? W0 : (z == 1 ? W1 : W2);
  OutT* C_out = z == 0 ? C0 : (z == 1 ? C1 : C2);
  const int h = (int)blockIdx.x + ((int)blockIdx.y << 6);  // [0,256)
  const int m0 = ((((h & 7) << 3) | ((h >> 3) & 7))) << 8;
  const int n0 = (h >> 6) << 8;
  const int tid = threadIdx.x;
  const int lane = tid & 63;
  const int w = tid >> 6;            // 0..7
  const int wm = w >> 2;             // 0..1  (row half)
  const int wn = w & 3;              // 0..3  (col quarter)
  const int fr = lane & 15;
  const int ksl = lane >> 4;         // 0..3
  // staging owner-group ids
  const int gb = wn >> 1;                    // B-half this wave reads/stages
  const int rb = (wm << 1) | (wn & 1);       // rank within B-group (0..3)
  const int ra = wn;                         // rank within A-group (0..3)

  f32x4 acc[8][4];
#pragma unroll
  for (int i = 0; i < 8; ++i)
#pragma unroll
    for (int j = 0; j < 4; ++j) acc[i][j] = (f32x4){0.f, 0.f, 0.f, 0.f};

  // one wave-load: 8 rows (64 lanes x 16B) starting at row r, linear LDS
  // dest, pre-swizzled global source slot.
#define STA(buf, kt, r)                                                       \
  {                                                                           \
    const int bc = (r) * 8;                                                   \
    const int c = bc + lane;                                                  \
    const int row = c >> 3;                                                   \
    const int gsl = (c & 7) ^ (row & 7);                                      \
    gload16(A + (size_t)(m0 + row) * K + (kt) + gsl * 8, &As[buf][bc * 8]);   \
  }
#define STB(buf, kt, r)                                                       \
  {                                                                           \
    const int bc = (r) * 8;                                                   \
    const int c = bc + lane;                                                  \
    const int row = c >> 3;                                                   \
    const int gsl = (c & 7) ^ (row & 7);                                      \
    gload16(W + (size_t)(n0 + row) * K + (kt) + gsl * 8, &Bs[buf][bc * 8]);   \
  }

#define LDSRD(bufp, row, sl) \
  (*(const short8*)&(bufp)[(row) * 64 + ((((sl) ^ ((row) & 7))) * 8)])

#define MFMA16(ar, bi, br)                                                    \
  {                                                                           \
    __builtin_amdgcn_s_setprio(1);                                            \
    _Pragma("unroll")                                                         \
    for (int i = 0; i < 4; ++i)                                               \
      _Pragma("unroll")                                                       \
      for (int j = 0; j < 4; ++j)                                             \
        acc[(bi) + i][j] = __builtin_amdgcn_mfma_f32_16x16x32_bf16(           \
            ar[i], br[j], acc[(bi) + i][j], 0, 0, 0);                         \
    __builtin_amdgcn_s_setprio(0);                                            \
  }

  const int nt = K / BK;             // 16
  // prologue: full stage of tile 0 (order irrelevant; drained once)
#pragma unroll
  for (int cc = 0; cc < 4; ++cc) {
    const int r = (w * 256 + cc * 64) >> 3;
    STA(0, 0, r);
    STB(0, 0, r);
  }
  asm volatile("s_waitcnt vmcnt(0)" ::: "memory");
  __builtin_amdgcn_s_barrier();
  FENCE();

  for (int t = 0; t < nt; ++t) {
    const int cur = t & 1, nb = cur ^ 1;
    const int kt1 = (t + 1) * BK;
    const bool st = (t + 1 < nt);
    const unsigned short* Ab = As[cur];
    const unsigned short* Bb = Bs[cur];
    const int sl0 = ksl, sl1 = 4 + ksl;
    short8 af[4], bf[4];
    // ======== phase 0: reads A[0-63]@ks0 + B@ks0; stage B-half rows 0-63 ===
#pragma unroll
    for (int i = 0; i < 4; ++i)
      af[i] = LDSRD(Ab, wm * 128 + i * 16 + fr, sl0);
#pragma unroll
    for (int j = 0; j < 4; ++j)
      bf[j] = LDSRD(Bb, wn * 64 + j * 16 + fr, sl0);
    if (st) {
      STB(nb, kt1, gb * 128 + rb * 16 + 0);
      STB(nb, kt1, gb * 128 + rb * 16 + 8);
      asm volatile("s_waitcnt vmcnt(4)" ::: "memory");
    } else {
      asm volatile("s_waitcnt vmcnt(2)" ::: "memory");
    }
    __builtin_amdgcn_s_barrier();
    FENCE();
    MFMA16(af, 0, bf);
    FENCE();
    __builtin_amdgcn_s_barrier();
    // ======== phase 1: reads A[64-127]@ks0; stage B-half rows 64-127 =======
#pragma unroll
    for (int i = 0; i < 4; ++i)
      af[i] = LDSRD(Ab, wm * 128 + (4 + i) * 16 + fr, sl0);
    if (st) {
      STB(nb, kt1, gb * 128 + 64 + rb * 16 + 0);
      STB(nb, kt1, gb * 128 + 64 + rb * 16 + 8);
      asm volatile("s_waitcnt vmcnt(4)" ::: "memory");
    } else {
      asm volatile("s_waitcnt vmcnt(0)" ::: "memory");
    }
    __builtin_amdgcn_s_barrier();
    FENCE();
    MFMA16(af, 4, bf);
    FENCE();
    __builtin_amdgcn_s_barrier();
    // ======== phase 2: reads A[0-63]@ks1 + B@ks1; stage A-half rows 0-63 ===
#pragma unroll
    for (int i = 0; i < 4; ++i)
      af[i] = LDSRD(Ab, wm * 128 + i * 16 + fr, sl1);
#pragma unroll
    for (int j = 0; j < 4; ++j)
      bf[j] = LDSRD(Bb, wn * 64 + j * 16 + fr, sl1);
    if (st) {
      STA(nb, kt1, wm * 128 + ra * 16 + 0);
      STA(nb, kt1, wm * 128 + ra * 16 + 8);
      asm volatile("s_waitcnt vmcnt(4)" ::: "memory");
    } else {
      asm volatile("s_waitcnt vmcnt(0)" ::: "memory");
    }
    __builtin_amdgcn_s_barrier();
    FENCE();
    MFMA16(af, 0, bf);
    FENCE();
    __builtin_amdgcn_s_barrier();
    // ======== phase 3: reads A[64-127]@ks1; stage A-half rows 64-127 =======
#pragma unroll
    for (int i = 0; i < 4; ++i)
      af[i] = LDSRD(Ab, wm * 128 + (4 + i) * 16 + fr, sl1);
    if (st) {
      STA(nb, kt1, wm * 128 + 64 + ra * 16 + 0);
      STA(nb, kt1, wm * 128 + 64 + ra * 16 + 8);
      asm volatile("s_waitcnt vmcnt(4)" ::: "memory");
    } else {
      asm volatile("s_waitcnt vmcnt(0)" ::: "memory");
    }
    __builtin_amdgcn_s_barrier();
    FENCE();
    MFMA16(af, 4, bf);
    FENCE();
    __builtin_amdgcn_s_barrier();
  }
#undef STA
#undef STB
#undef LDSRD
#undef MFMA16

  // C/D layout: col = lane&15, row = (lane>>4)*4 + q
  const int orow = (lane >> 4) * 4;
  const int ocol = lane & 15;
#pragma unroll
  for (int i = 0; i < 8; ++i)
#pragma unroll
    for (int j = 0; j < 4; ++j) {
      const size_t rbase = (size_t)(m0 + wm * 128 + i * 16 + orow);
      const int cb = n0 + wn * 64 + j * 16 + ocol;
#pragma unroll
      for (int q = 0; q < 4; ++q) {
        const float vq = acc[i][j][q];
        if constexpr (sizeof(OutT) == 2)
          C_out[(rbase + q) * N + cb] = (OutT)f2b(vq);
        else
          C_out[(rbase + q) * N + cb] = (OutT)vq;
      }
    }
}

// ---------------- WKV chunked scan (1 ch/thread, single-exp updates) -------
__global__ void wkv_phase1(const unsigned short* __restrict__ keyb,
                           const unsigned short* __restrict__ valb,
                           const float* __restrict__ td,
                           float* __restrict__ s_num,
                           float* __restrict__ s_den,
                           float* __restrict__ s_mx) {
  const int g = blockIdx.x * blockDim.x + threadIdx.x;  // [0, B*NCH*C)
  const int c = g & (Cc - 1);
  const int j = (g / Cc) & (WKV_NCH - 1);
  const int b = g / (Cc * WKV_NCH);
  const float w = -__expf(td[c]);
  float num = 0.f, den = 0.f, mx = -1e38f;
  size_t idx = ((size_t)b * Tc + (size_t)j * WKV_L) * Cc + c;
#pragma unroll 4
  for (int i = 0; i < WKV_L; ++i, idx += Cc) {
    const float kt = b2f(keyb[idx]);
    const float vt = b2f(valb[idx]);
    const float mw = mx + w;
    const bool cg = mw >= kt;
    const float d = __expf(cg ? kt - mw : mw - kt);
    const float a1 = cg ? 1.f : d;
    const float a2 = cg ? d : 1.f;
    num = a1 * num + a2 * vt;
    den = a1 * den + a2;
    mx = cg ? mw : kt;
  }
  s_num[g] = num; s_den[g] = den; s_mx[g] = mx;
}

__global__ void wkv_phase2(const float* __restrict__ td,
                           float* __restrict__ s_num,
                           float* __restrict__ s_den,
                           float* __restrict__ s_mx) {
  const int g = blockIdx.x * blockDim.x + threadIdx.x;  // [0, B*C)
  const int c = g & (Cc - 1);
  const int b = g / Cc;
  const float Lw = -__expf(td[c]) * (float)WKV_L;
  float num = 0.f, den = 0.f, mx = -1e38f;
  size_t base = (size_t)b * WKV_NCH * Cc + c;
  for (int j = 0; j < WKV_NCH; ++j) {
    const size_t s = base + (size_t)j * Cc;
    const float ln = s_num[s], ld = s_den[s], lm = s_mx[s];
    s_num[s] = num; s_den[s] = den; s_mx[s] = mx;  // exclusive prefix
    const float md = mx + Lw;
    const bool cg = md >= lm;
    const float d = __expf(cg ? lm - md : md - lm);
    const float e1 = cg ? 1.f : d;
    const float e2 = cg ? d : 1.f;
    num = e1 * num + e2 * ln;
    den = e1 * den + e2 * ld;
    mx = cg ? md : lm;
  }
}

__global__ void wkv_phase3(const unsigned short* __restrict__ keyb,
                           const unsigned short* __restrict__ valb,
                           const unsigned short* __restrict__ recb,
                           const float* __restrict__ td,
                           const float* __restrict__ tf,
                           const float* __restrict__ s_num,
                           const float* __restrict__ s_den,
                           const float* __restrict__ s_mx,
                           unsigned short* __restrict__ rwkv) {
  const int g = blockIdx.x * blockDim.x + threadIdx.x;  // [0, B*NCH*C)
  const int c = g & (Cc - 1);
  const int j = (g / Cc) & (WKV_NCH - 1);
  const int b = g / (Cc * WKV_NCH);
  const float w = -__expf(td[c]);
  const float u = tf[c];
  float num = s_num[g], den = s_den[g], mx = s_mx[g];
  size_t idx = ((size_t)b * Tc + (size_t)j * WKV_L) * Cc + c;
#pragma unroll 2
  for (int i = 0; i < WKV_L; ++i, idx += Cc) {
    const float kt = b2f(keyb[idx]);
    const float vt = b2f(valb[idx]);
    const float rt = b2f(recb[idx]);
    const float ku = kt + u;
    const bool co = mx >= ku;
    const float dd = __expf(co ? ku - mx : mx - ku);
    const float e1 = co ? 1.f : dd;
    const float e2 = co ? dd : 1.f;
    const float out = (e1 * num + e2 * vt) / (e1 * den + e2);
    const float sr = 1.f / (1.f + __expf(-rt));
    rwkv[idx] = f2b(sr * out);
    const float mw = mx + w;
    const bool cg = mw >= kt;
    const float du = __expf(cg ? kt - mw : mw - kt);
    const float a1 = cg ? 1.f : du;
    const float a2 = cg ? du : 1.f;
    num = a1 * num + a2 * vt;
    den = a1 * den + a2;
    mx = cg ? mw : kt;
  }
}

extern "C" void kernel_launch(void* const* d_in, const int* in_sizes, int n_in,
                              void* d_out, int out_size, void* d_ws, size_t ws_size,
                              hipStream_t stream) {
  const float* x   = (const float*)d_in[0];
  const float* Wk  = (const float*)d_in[1];
  const float* Wv  = (const float*)d_in[2];
  const float* Wr  = (const float*)d_in[3];
  const float* Wo  = (const float*)d_in[4];
  const float* td  = (const float*)d_in[5];
  const float* tf  = (const float*)d_in[6];
  const float* tmk = (const float*)d_in[7];
  const float* tmv = (const float*)d_in[8];
  const float* tmr = (const float*)d_in[9];

  const long BT = (long)Bc * Tc;     // 16384
  const long NE = BT * Cc;           // 16,777,216
  const long CC = (long)Cc * Cc;     // 1,048,576

  // Workspace carve (~200 MB)
  char* p = (char*)d_ws;
  unsigned short* Wk_b = (unsigned short*)p; p += CC * 2;
  unsigned short* Wv_b = (unsigned short*)p; p += CC * 2;
  unsigned short* Wr_b = (unsigned short*)p; p += CC * 2;
  unsigned short* Wo_b = (unsigned short*)p; p += CC * 2;
  unsigned short* kin  = (unsigned short*)p; p += NE * 2;
  unsigned short* vin  = (unsigned short*)p; p += NE * 2;
  unsigned short* rin  = (unsigned short*)p; p += NE * 2;
  unsigned short* keyb = (unsigned short*)p; p += NE * 2;
  unsigned short* valb = (unsigned short*)p; p += NE * 2;
  unsigned short* recb = (unsigned short*)p; p += NE * 2;
  // aliases: rwkv reuses kin (dead after key GEMM); s_* reuse vin (dead after
  // value GEMM). 3 x 2MB well within vin's 32MB.
  unsigned short* rwkv = kin;
  const long NS = (long)Bc * WKV_NCH * Cc;  // 524288
  float* s_num = (float*)vin;
  float* s_den = s_num + NS;
  float* s_mx  = s_den + NS;

  // 1. weights -> bf16 (single dispatch)
  {
    dim3 g((unsigned)(CC / 4 / 256), 4), b_(256);
    convert4_kernel<<<g, b_, 0, stream>>>(Wk, Wv, Wr, Wo,
                                          Wk_b, Wv_b, Wr_b, Wo_b);
  }

  // 2. time-mix + cast
  mix3_kernel<<<2048, 256, 0, stream>>>(x, tmk, tmv, tmr, kin, vin, rin, NE / 4);

  // 3. K/V/R GEMMs (K=1024), batched via blockIdx.z, bf16 outputs
  {
    dim3 grid((unsigned)(BT / 256), (unsigned)(Cc / 256), 3), blk(512);
    gemm256e<unsigned short><<<grid, blk, 0, stream>>>(
        kin, Wk_b, keyb, vin, Wv_b, valb, rin, Wr_b, recb, Cc, Cc);
  }

  // 4. WKV chunked scan + sigmoid gate -> rwkv bf16
  wkv_phase1<<<2048, 256, 0, stream>>>(keyb, valb, td, s_num, s_den, s_mx);
  wkv_phase2<<<32, 256, 0, stream>>>(td, s_num, s_den, s_mx);
  wkv_phase3<<<2048, 256, 0, stream>>>(keyb, valb, recb, td, tf,
                                       s_num, s_den, s_mx, rwkv);

  // 5. output GEMM -> d_out (f32)
  {
    dim3 grid((unsigned)(BT / 256), (unsigned)(Cc / 256), 1), blk(512);
    gemm256e<float><<<grid, blk, 0, stream>>>(
        rwkv, Wo_b, (float*)d_out, rwkv, Wo_b, (float*)d_out,
        rwkv, Wo_b, (float*)d_out, Cc, Cc);
  }
}